// Round 1
// baseline (537.486 us; speedup 1.0000x reference)
//
#include <hip/hip_runtime.h>
#include <stdint.h>
#include <math.h>

#define TOK 2048
#define DMODEL 4096
#define QKV_LD 6144   // q(4096) | k(1024) | v(1024)

typedef __attribute__((ext_vector_type(8))) short short8;
typedef __attribute__((ext_vector_type(8))) __bf16 bf16x8;
typedef __attribute__((ext_vector_type(4))) float f32x4;

__device__ __forceinline__ unsigned short f2bf(float f) {
  unsigned u = __float_as_uint(f);
  u += 0x7fffu + ((u >> 16) & 1u);   // RNE
  return (unsigned short)(u >> 16);
}

__device__ __forceinline__ void gl16(const void* g, void* l) {
  __builtin_amdgcn_global_load_lds((__attribute__((address_space(1))) void*)g,
                                   (__attribute__((address_space(3))) void*)l,
                                   16, 0, 0);
}

__device__ __forceinline__ f32x4 mfma16(short8 a, short8 b, f32x4 c) {
  return __builtin_amdgcn_mfma_f32_16x16x32_bf16(__builtin_bit_cast(bf16x8, a),
                                                 __builtin_bit_cast(bf16x8, b),
                                                 c, 0, 0, 0);
}

// ---------------- RMSNorm: fp32 x -> bf16 h ----------------
__global__ __launch_bounds__(256) void k_rmsnorm(const float* __restrict__ x,
                                                 const float* __restrict__ w,
                                                 unsigned short* __restrict__ h) {
  const int row = blockIdx.x;
  const float* xr = x + (size_t)row * DMODEL;
  float4 v[4];
  float ss = 0.f;
#pragma unroll
  for (int i = 0; i < 4; ++i) {
    v[i] = *(const float4*)(xr + threadIdx.x * 4 + i * 1024);
    ss += v[i].x * v[i].x + v[i].y * v[i].y + v[i].z * v[i].z + v[i].w * v[i].w;
  }
#pragma unroll
  for (int m = 1; m < 64; m <<= 1) ss += __shfl_xor(ss, m, 64);
  __shared__ float ws4[4];
  if ((threadIdx.x & 63) == 0) ws4[threadIdx.x >> 6] = ss;
  __syncthreads();
  const float scale = rsqrtf((ws4[0] + ws4[1] + ws4[2] + ws4[3]) * (1.0f / DMODEL) + 1e-5f);
  unsigned short* hr = h + (size_t)row * DMODEL;
#pragma unroll
  for (int i = 0; i < 4; ++i) {
    int col = threadIdx.x * 4 + i * 1024;
    float4 wv = *(const float4*)(w + col);
    uint2 o;
    o.x = (unsigned)f2bf(v[i].x * scale * wv.x) | ((unsigned)f2bf(v[i].y * scale * wv.y) << 16);
    o.y = (unsigned)f2bf(v[i].z * scale * wv.z) | ((unsigned)f2bf(v[i].w * scale * wv.w) << 16);
    *(uint2*)(hr + col) = o;
  }
}

// ------- Weight convert+transpose: W[K][N] fp32 -> WT[N][K] bf16 -------
__global__ __launch_bounds__(256) void k_wconvert(const float* __restrict__ W,
                                                  unsigned short* __restrict__ WT,
                                                  int K, int N) {
  __shared__ unsigned short tile[64][65];
  const int n0 = blockIdx.x * 64, k0 = blockIdx.y * 64;
  const int t = threadIdx.x;
  {
    const int r = t >> 2, c0 = (t & 3) * 16;
    const float* src = W + (size_t)(k0 + r) * N + n0 + c0;
#pragma unroll
    for (int i = 0; i < 4; ++i) {
      float4 f = *(const float4*)(src + i * 4);
      tile[r][c0 + i * 4 + 0] = f2bf(f.x);
      tile[r][c0 + i * 4 + 1] = f2bf(f.y);
      tile[r][c0 + i * 4 + 2] = f2bf(f.z);
      tile[r][c0 + i * 4 + 3] = f2bf(f.w);
    }
  }
  __syncthreads();
  {
    const int n = t >> 2, c0 = (t & 3) * 16;
    unsigned short* dst = WT + (size_t)(n0 + n) * K + k0 + c0;
    unsigned short v[16];
#pragma unroll
    for (int i = 0; i < 16; ++i) v[i] = tile[c0 + i][n];
    uint4 o0, o1;
    o0.x = v[0] | ((unsigned)v[1] << 16);  o0.y = v[2] | ((unsigned)v[3] << 16);
    o0.z = v[4] | ((unsigned)v[5] << 16);  o0.w = v[6] | ((unsigned)v[7] << 16);
    o1.x = v[8] | ((unsigned)v[9] << 16);  o1.y = v[10] | ((unsigned)v[11] << 16);
    o1.z = v[12] | ((unsigned)v[13] << 16); o1.w = v[14] | ((unsigned)v[15] << 16);
    *(uint4*)dst = o0;
    *(uint4*)(dst + 8) = o1;
  }
}

// ------------- GEMM: A[M][K]bf16 x BT[N][K]bf16 -> C (m97 structure) -------------
// RESID=0: C bf16[M][N].  RESID=1: C fp32[M][N] = acc + resid.
template <int RESID>
__global__ __launch_bounds__(256) void k_gemm(const unsigned short* __restrict__ A,
                                              const unsigned short* __restrict__ BT,
                                              const float* __restrict__ resid,
                                              void* __restrict__ Cout,
                                              int M, int N, int K) {
  __shared__ __align__(16) unsigned short As[128 * 32];
  __shared__ __align__(16) unsigned short Bs[128 * 32];
  const int n0 = blockIdx.x * 128, m0 = blockIdx.y * 128;
  const int tid = threadIdx.x, lane = tid & 63, w = tid >> 6;
  const int wr = w >> 1, wc = w & 1;
  const int lr = lane & 15, lh = lane >> 4;

  const f32x4 zf = {0.f, 0.f, 0.f, 0.f};
  f32x4 acc[4][4];
#pragma unroll
  for (int mi = 0; mi < 4; ++mi)
#pragma unroll
    for (int ni = 0; ni < 4; ++ni) acc[mi][ni] = zf;

  for (int k0 = 0; k0 < K; k0 += 32) {
    __syncthreads();
#pragma unroll
    for (int c = 0; c < 2; ++c) {
      const int s = c * 256 + w * 64 + lane;    // 16B slot id 0..511
      const int row = s >> 2, cp = s & 3;
      gl16(A + (size_t)(m0 + row) * K + k0 + cp * 8,
           (char*)As + (c * 256 + w * 64) * 16);
      gl16(BT + (size_t)(n0 + row) * K + k0 + cp * 8,
           (char*)Bs + (c * 256 + w * 64) * 16);
    }
    __syncthreads();

    short8 af[4], bf[4];
#pragma unroll
    for (int mi = 0; mi < 4; ++mi)
      af[mi] = *(const short8*)(As + (wr * 64 + mi * 16 + lr) * 32 + lh * 8);
#pragma unroll
    for (int ni = 0; ni < 4; ++ni)
      bf[ni] = *(const short8*)(Bs + (wc * 64 + ni * 16 + lr) * 32 + lh * 8);
#pragma unroll
    for (int mi = 0; mi < 4; ++mi)
#pragma unroll
      for (int ni = 0; ni < 4; ++ni)
        acc[mi][ni] = mfma16(af[mi], bf[ni], acc[mi][ni]);
  }

  // epilogue: C row = 4*lh + r, col = lr within each 16x16 tile
#pragma unroll
  for (int mi = 0; mi < 4; ++mi) {
#pragma unroll
    for (int ni = 0; ni < 4; ++ni) {
      const int colg = n0 + wc * 64 + ni * 16 + lr;
#pragma unroll
      for (int r = 0; r < 4; ++r) {
        const int rowg = m0 + wr * 64 + mi * 16 + 4 * lh + r;
        if (RESID) {
          ((float*)Cout)[(size_t)rowg * N + colg] =
              acc[mi][ni][r] + resid[(size_t)rowg * N + colg];
        } else {
          ((unsigned short*)Cout)[(size_t)rowg * N + colg] = f2bf(acc[mi][ni][r]);
        }
      }
    }
  }
}

// ---------------- RoPE (in-place on q|k columns 0..5119) ----------------
__global__ __launch_bounds__(256) void k_rope(unsigned short* __restrict__ qkv,
                                              const float* __restrict__ rc,
                                              const float* __restrict__ rs) {
  const int row = blockIdx.y;
  const int p = blockIdx.x * 256 + threadIdx.x;  // pair 0..2559
  const int col = p * 2;
  const int d = col & 127;
  unsigned short* ptr = qkv + (size_t)row * QKV_LD + col;
  const unsigned both = *(const unsigned*)ptr;
  const float x0 = __uint_as_float((both & 0xffffu) << 16);
  const float x1 = __uint_as_float(both & 0xffff0000u);
  const float c0 = rc[row * 128 + d], c1 = rc[row * 128 + d + 1];
  const float s0 = rs[row * 128 + d], s1 = rs[row * 128 + d + 1];
  const float y0 = x0 * c0 - x1 * s0;
  const float y1 = x1 * c1 + x0 * s1;
  *(unsigned*)ptr = (unsigned)f2bf(y0) | ((unsigned)f2bf(y1) << 16);
}

// ---------------- Flash attention, causal, GQA ----------------
// grid (32 q-tiles, 32 heads), 256 threads = 4 waves x 16 q-rows.
__global__ __launch_bounds__(256) void k_attn(const unsigned short* __restrict__ qkv,
                                              unsigned short* __restrict__ aout) {
  __shared__ __align__(16) unsigned short Ks[32 * 128];   // XOR-swizzled
  __shared__ __align__(16) unsigned short Vt[128 * 40];   // V transposed, stride 40
  __shared__ __align__(16) unsigned short Ps[4][16 * 32];
  const int qt = blockIdx.x, head = blockIdx.y;
  const int hkv = head >> 2;
  const int q0 = qt * 64;
  const int tid = threadIdx.x, lane = tid & 63, w = tid >> 6;
  const int lr = lane & 15, lh = lane >> 4;
  const float scale = 0.08838834764831845f;   // 1/sqrt(128)
  const f32x4 zf = {0.f, 0.f, 0.f, 0.f};

  // Q fragments (A operand rows = lr)
  short8 qf[4];
  {
    const unsigned short* qbase = qkv + (size_t)(q0 + w * 16 + lr) * QKV_LD + head * 128;
#pragma unroll
    for (int kd = 0; kd < 4; ++kd)
      qf[kd] = *(const short8*)(qbase + kd * 32 + lh * 8);
  }

  f32x4 oacc[8];
#pragma unroll
  for (int vt = 0; vt < 8; ++vt) oacc[vt] = zf;
  float Mr[4], Lr[4];
#pragma unroll
  for (int r = 0; r < 4; ++r) { Mr[r] = -INFINITY; Lr[r] = 0.f; }

  const int nt = 2 * qt + 2;
  for (int t = 0; t < nt; ++t) {
    const int kv0 = t * 32;
    __syncthreads();
    // stage K (32 rows x 128) via global_load_lds, XOR-swizzled source chunks
#pragma unroll
    for (int c = 0; c < 2; ++c) {
      const int s = c * 256 + w * 64 + lane;
      const int row = s >> 4, cp = s & 15;
      gl16(qkv + (size_t)(kv0 + row) * QKV_LD + 4096 + hkv * 128 + ((cp ^ (row & 7)) * 8),
           (char*)Ks + (c * 256 + w * 64) * 16);
    }
    // stage V transposed (reg path)
    {
      const int cb = tid >> 5, r = tid & 31;
      const unsigned short* vsrc = qkv + (size_t)(kv0 + r) * QKV_LD + 5120 + hkv * 128 + cb * 16;
      short8 v0 = *(const short8*)(vsrc);
      short8 v1 = *(const short8*)(vsrc + 8);
#pragma unroll
      for (int i = 0; i < 8; ++i) {
        Vt[(cb * 16 + i) * 40 + r] = (unsigned short)v0[i];
        Vt[(cb * 16 + 8 + i) * 40 + r] = (unsigned short)v1[i];
      }
    }
    __syncthreads();

    // QK^T: S[16 x 32]
    f32x4 sacc[2];
    sacc[0] = zf; sacc[1] = zf;
#pragma unroll
    for (int ct = 0; ct < 2; ++ct) {
      const int row = ct * 16 + lr;
#pragma unroll
      for (int kd = 0; kd < 4; ++kd) {
        short8 kf = *(const short8*)((const char*)Ks + row * 256 + (((kd * 4 + lh) ^ (row & 7)) * 16));
        sacc[ct] = mfma16(qf[kd], kf, sacc[ct]);
      }
    }

    // mask + online softmax (rows live on 16-lane groups)
    float p0v[4], p1v[4], scv[4];
#pragma unroll
    for (int r = 0; r < 4; ++r) {
      const int qrow = q0 + w * 16 + 4 * lh + r;
      float s0 = sacc[0][r] * scale, s1 = sacc[1][r] * scale;
      if (kv0 + lr > qrow) s0 = -INFINITY;
      if (kv0 + 16 + lr > qrow) s1 = -INFINITY;
      float tmax = fmaxf(s0, s1);
      tmax = fmaxf(tmax, __shfl_xor(tmax, 1, 16));
      tmax = fmaxf(tmax, __shfl_xor(tmax, 2, 16));
      tmax = fmaxf(tmax, __shfl_xor(tmax, 4, 16));
      tmax = fmaxf(tmax, __shfl_xor(tmax, 8, 16));
      const float mnew = fmaxf(Mr[r], tmax);
      const float sc = __expf(Mr[r] - mnew);
      Mr[r] = mnew;
      const float p0 = __expf(s0 - mnew);
      const float p1 = __expf(s1 - mnew);
      float ps = p0 + p1;
      ps += __shfl_xor(ps, 1, 16);
      ps += __shfl_xor(ps, 2, 16);
      ps += __shfl_xor(ps, 4, 16);
      ps += __shfl_xor(ps, 8, 16);
      Lr[r] = Lr[r] * sc + ps;
      p0v[r] = p0; p1v[r] = p1; scv[r] = sc;
    }
#pragma unroll
    for (int vt = 0; vt < 8; ++vt)
#pragma unroll
      for (int r = 0; r < 4; ++r) oacc[vt][r] *= scv[r];

    // P -> LDS (per-wave), then PV
    unsigned short* pw = Ps[w];
#pragma unroll
    for (int r = 0; r < 4; ++r) {
      pw[(4 * lh + r) * 32 + lr] = f2bf(p0v[r]);
      pw[(4 * lh + r) * 32 + 16 + lr] = f2bf(p1v[r]);
    }
    asm volatile("s_waitcnt lgkmcnt(0)" ::: "memory");
    const short8 pf = *(const short8*)(pw + lr * 32 + lh * 8);
#pragma unroll
    for (int vt = 0; vt < 8; ++vt) {
      short8 vf = *(const short8*)(Vt + (vt * 16 + lr) * 40 + lh * 8);
      oacc[vt] = mfma16(pf, vf, oacc[vt]);
    }
  }

  // epilogue
#pragma unroll
  for (int r = 0; r < 4; ++r) {
    const float inv = 1.0f / Lr[r];
    const size_t rowoff = (size_t)(q0 + w * 16 + 4 * lh + r) * DMODEL + head * 128;
#pragma unroll
    for (int vt = 0; vt < 8; ++vt)
      aout[rowoff + vt * 16 + lr] = f2bf(oacc[vt][r] * inv);
  }
}

extern "C" void kernel_launch(void* const* d_in, const int* in_sizes, int n_in,
                              void* d_out, int out_size, void* d_ws, size_t ws_size,
                              hipStream_t stream) {
  (void)in_sizes; (void)n_in; (void)out_size; (void)ws_size;
  const float* x     = (const float*)d_in[0];
  const float* r_cos = (const float*)d_in[1];
  const float* r_sin = (const float*)d_in[2];
  const float* wnorm = (const float*)d_in[3];
  const float* wq    = (const float*)d_in[4];
  const float* wk    = (const float*)d_in[5];
  const float* wv    = (const float*)d_in[6];
  const float* wo    = (const float*)d_in[7];

  // ws layout (bf16 elements): bufA 8.39M | qkvb 12.58M | wT 25.17M  => 92.3 MB total
  unsigned short* bufA = (unsigned short*)d_ws;                 // h, later attn-out
  unsigned short* qkvb = bufA + (size_t)TOK * DMODEL;           // [2048][6144]
  unsigned short* wT   = qkvb + (size_t)TOK * QKV_LD;           // wqkv^T, later wo^T

  k_rmsnorm<<<TOK, 256, 0, stream>>>(x, wnorm, bufA);
  k_wconvert<<<dim3(64, 64), 256, 0, stream>>>(wq, wT, DMODEL, 4096);
  k_wconvert<<<dim3(16, 64), 256, 0, stream>>>(wk, wT + (size_t)4096 * DMODEL, DMODEL, 1024);
  k_wconvert<<<dim3(16, 64), 256, 0, stream>>>(wv, wT + (size_t)5120 * DMODEL, DMODEL, 1024);
  k_gemm<0><<<dim3(48, 16), 256, 0, stream>>>(bufA, wT, nullptr, qkvb, TOK, QKV_LD, DMODEL);
  k_wconvert<<<dim3(64, 64), 256, 0, stream>>>(wo, wT, DMODEL, 4096);   // overlay: wo^T
  k_rope<<<dim3(10, TOK), 256, 0, stream>>>(qkvb, r_cos, r_sin);
  k_attn<<<dim3(32, 32), 256, 0, stream>>>(qkvb, bufA);
  k_gemm<1><<<dim3(32, 16), 256, 0, stream>>>(bufA, wT, x, d_out, TOK, DMODEL, DMODEL);
}

// Round 3
// 402.222 us; speedup vs baseline: 1.3363x; 1.3363x over previous
//
#include <hip/hip_runtime.h>
#include <stdint.h>
#include <math.h>

#define TOK 2048
#define DMODEL 4096
#define QKV_LD 5120   // q(4096) | k(1024); V goes transposed to vtg
#define KVB 64
#define PS_LD 72      // 64 kv + 8 pad (P-tile LDS stride)

typedef __attribute__((ext_vector_type(8))) short short8;
typedef __attribute__((ext_vector_type(4))) short short4v;
typedef __attribute__((ext_vector_type(8))) __bf16 bf16x8;
typedef __attribute__((ext_vector_type(4))) float f32x4;

__device__ __forceinline__ unsigned short f2bf(float f) {
  unsigned u = __float_as_uint(f);
  u += 0x7fffu + ((u >> 16) & 1u);   // RNE
  return (unsigned short)(u >> 16);
}

__device__ __forceinline__ void gl16(const void* g, void* l) {
  __builtin_amdgcn_global_load_lds((__attribute__((address_space(1))) void*)g,
                                   (__attribute__((address_space(3))) void*)l,
                                   16, 0, 0);
}

__device__ __forceinline__ f32x4 mfma16(short8 a, short8 b, f32x4 c) {
  return __builtin_amdgcn_mfma_f32_16x16x32_bf16(__builtin_bit_cast(bf16x8, a),
                                                 __builtin_bit_cast(bf16x8, b),
                                                 c, 0, 0, 0);
}

__device__ __forceinline__ float fexp2(float x) {
  float r;
  asm("v_exp_f32 %0, %1" : "=v"(r) : "v"(x));
  return r;
}

// ---------------- RMSNorm: fp32 x -> bf16 h ----------------
__global__ __launch_bounds__(256) void k_rmsnorm(const float* __restrict__ x,
                                                 const float* __restrict__ w,
                                                 unsigned short* __restrict__ h) {
  const int row = blockIdx.x;
  const float* xr = x + (size_t)row * DMODEL;
  float4 v[4];
  float ss = 0.f;
#pragma unroll
  for (int i = 0; i < 4; ++i) {
    v[i] = *(const float4*)(xr + threadIdx.x * 4 + i * 1024);
    ss += v[i].x * v[i].x + v[i].y * v[i].y + v[i].z * v[i].z + v[i].w * v[i].w;
  }
#pragma unroll
  for (int m = 1; m < 64; m <<= 1) ss += __shfl_xor(ss, m, 64);
  __shared__ float ws4[4];
  if ((threadIdx.x & 63) == 0) ws4[threadIdx.x >> 6] = ss;
  __syncthreads();
  const float scale = rsqrtf((ws4[0] + ws4[1] + ws4[2] + ws4[3]) * (1.0f / DMODEL) + 1e-5f);
  unsigned short* hr = h + (size_t)row * DMODEL;
#pragma unroll
  for (int i = 0; i < 4; ++i) {
    int col = threadIdx.x * 4 + i * 1024;
    float4 wv = *(const float4*)(w + col);
    uint2 o;
    o.x = (unsigned)f2bf(v[i].x * scale * wv.x) | ((unsigned)f2bf(v[i].y * scale * wv.y) << 16);
    o.y = (unsigned)f2bf(v[i].z * scale * wv.z) | ((unsigned)f2bf(v[i].w * scale * wv.w) << 16);
    *(uint2*)(hr + col) = o;
  }
}

// ------- Weight convert+transpose: W[K][N] fp32 -> WT[N][K] bf16 -------
__global__ __launch_bounds__(256) void k_wconvert(const float* __restrict__ W,
                                                  unsigned short* __restrict__ WT,
                                                  int K, int N) {
  __shared__ unsigned short tile[64][65];
  const int n0 = blockIdx.x * 64, k0 = blockIdx.y * 64;
  const int t = threadIdx.x;
  {
    const int r = t >> 2, c0 = (t & 3) * 16;
    const float* src = W + (size_t)(k0 + r) * N + n0 + c0;
#pragma unroll
    for (int i = 0; i < 4; ++i) {
      float4 f = *(const float4*)(src + i * 4);
      tile[r][c0 + i * 4 + 0] = f2bf(f.x);
      tile[r][c0 + i * 4 + 1] = f2bf(f.y);
      tile[r][c0 + i * 4 + 2] = f2bf(f.z);
      tile[r][c0 + i * 4 + 3] = f2bf(f.w);
    }
  }
  __syncthreads();
  {
    const int n = t >> 2, c0 = (t & 3) * 16;
    unsigned short* dst = WT + (size_t)(n0 + n) * K + k0 + c0;
    unsigned short v[16];
#pragma unroll
    for (int i = 0; i < 16; ++i) v[i] = tile[c0 + i][n];
    uint4 o0, o1;
    o0.x = v[0] | ((unsigned)v[1] << 16);  o0.y = v[2] | ((unsigned)v[3] << 16);
    o0.z = v[4] | ((unsigned)v[5] << 16);  o0.w = v[6] | ((unsigned)v[7] << 16);
    o1.x = v[8] | ((unsigned)v[9] << 16);  o1.y = v[10] | ((unsigned)v[11] << 16);
    o1.z = v[12] | ((unsigned)v[13] << 16); o1.w = v[14] | ((unsigned)v[15] << 16);
    *(uint4*)dst = o0;
    *(uint4*)(dst + 8) = o1;
  }
}

// ------------- GEMM: A[M][K]bf16 x BT[N][K]bf16 (m97 structure) -------------
// MODE=0: qkv output — cols <5120 -> bf16 qkvb (stride QKV_LD), cols >=5120 ->
//         vtg transposed ([col-5120][token]).  MODE=1: fp32 C = acc + resid.
template <int MODE>
__global__ __launch_bounds__(256) void k_gemm(const unsigned short* __restrict__ A,
                                              const unsigned short* __restrict__ BT,
                                              const float* __restrict__ resid,
                                              void* __restrict__ Cout,
                                              unsigned short* __restrict__ vtg,
                                              int M, int N, int K) {
  __shared__ __align__(16) unsigned short As[128 * 32];
  __shared__ __align__(16) unsigned short Bs[128 * 32];
  const int n0 = blockIdx.x * 128, m0 = blockIdx.y * 128;
  const int tid = threadIdx.x, lane = tid & 63, w = tid >> 6;
  const int wr = w >> 1, wc = w & 1;
  const int lr = lane & 15, lh = lane >> 4;

  const f32x4 zf = {0.f, 0.f, 0.f, 0.f};
  f32x4 acc[4][4];
#pragma unroll
  for (int mi = 0; mi < 4; ++mi)
#pragma unroll
    for (int ni = 0; ni < 4; ++ni) acc[mi][ni] = zf;

  for (int k0 = 0; k0 < K; k0 += 32) {
    __syncthreads();
#pragma unroll
    for (int c = 0; c < 2; ++c) {
      const int s = c * 256 + w * 64 + lane;    // 16B slot id 0..511
      const int row = s >> 2, cp = s & 3;
      gl16(A + (size_t)(m0 + row) * K + k0 + cp * 8,
           (char*)As + (c * 256 + w * 64) * 16);
      gl16(BT + (size_t)(n0 + row) * K + k0 + cp * 8,
           (char*)Bs + (c * 256 + w * 64) * 16);
    }
    __syncthreads();

    short8 af[4], bf[4];
#pragma unroll
    for (int mi = 0; mi < 4; ++mi)
      af[mi] = *(const short8*)(As + (wr * 64 + mi * 16 + lr) * 32 + lh * 8);
#pragma unroll
    for (int ni = 0; ni < 4; ++ni)
      bf[ni] = *(const short8*)(Bs + (wc * 64 + ni * 16 + lr) * 32 + lh * 8);
#pragma unroll
    for (int mi = 0; mi < 4; ++mi)
#pragma unroll
      for (int ni = 0; ni < 4; ++ni)
        acc[mi][ni] = mfma16(af[mi], bf[ni], acc[mi][ni]);
  }

  // epilogue: C row = 4*lh + r, col = lr within each 16x16 tile
#pragma unroll
  for (int mi = 0; mi < 4; ++mi) {
#pragma unroll
    for (int ni = 0; ni < 4; ++ni) {
      const int colg = n0 + wc * 64 + ni * 16 + lr;
      if (MODE == 1) {
#pragma unroll
        for (int r = 0; r < 4; ++r) {
          const int rowg = m0 + wr * 64 + mi * 16 + 4 * lh + r;
          ((float*)Cout)[(size_t)rowg * N + colg] =
              acc[mi][ni][r] + resid[(size_t)rowg * N + colg];
        }
      } else if (colg >= 5120) {
        short4v o;
#pragma unroll
        for (int r = 0; r < 4; ++r) o[r] = (short)f2bf(acc[mi][ni][r]);
        const int rowg0 = m0 + wr * 64 + mi * 16 + 4 * lh;
        *(short4v*)(vtg + (size_t)(colg - 5120) * TOK + rowg0) = o;
      } else {
#pragma unroll
        for (int r = 0; r < 4; ++r) {
          const int rowg = m0 + wr * 64 + mi * 16 + 4 * lh + r;
          ((unsigned short*)Cout)[(size_t)rowg * QKV_LD + colg] = f2bf(acc[mi][ni][r]);
        }
      }
    }
  }
}

// ---------------- RoPE (in-place on q|k columns 0..5119) ----------------
__global__ __launch_bounds__(256) void k_rope(unsigned short* __restrict__ qkv,
                                              const float* __restrict__ rc,
                                              const float* __restrict__ rs) {
  const int row = blockIdx.y;
  const int p = blockIdx.x * 256 + threadIdx.x;  // pair 0..2559
  const int col = p * 2;
  const int d = col & 127;
  unsigned short* ptr = qkv + (size_t)row * QKV_LD + col;
  const unsigned both = *(const unsigned*)ptr;
  const float x0 = __uint_as_float((both & 0xffffu) << 16);
  const float x1 = __uint_as_float(both & 0xffff0000u);
  const float c0 = rc[row * 128 + d], c1 = rc[row * 128 + d + 1];
  const float s0 = rs[row * 128 + d], s1 = rs[row * 128 + d + 1];
  const float y0 = x0 * c0 - x1 * s0;
  const float y1 = x1 * c1 + x0 * s1;
  *(unsigned*)ptr = (unsigned)f2bf(y0) | ((unsigned)f2bf(y1) << 16);
}

// ---------------- Flash attention, causal, GQA ----------------
// grid (16 pairs, 32 heads); block = 4 waves x 16 q-rows = 64 q-rows.
// Each block does q-tile i then q-tile 31-i -> exactly 33 KV-tiles of 64.
__global__ __launch_bounds__(256) void k_attn(const unsigned short* __restrict__ qkv,
                                              const unsigned short* __restrict__ vtg,
                                              unsigned short* __restrict__ aout) {
  __shared__ __align__(16) unsigned short Ks[KVB * 128];      // 16KB, XOR-swizzled
  __shared__ __align__(16) unsigned short Vt[128 * KVB];      // 16KB, XOR-swizzled (V^T)
  __shared__ __align__(16) unsigned short Ps[4][16 * PS_LD];  // per-wave P, stride 72
  const int head = blockIdx.y;
  const int hkv = head >> 2;
  const int tid = threadIdx.x, lane = tid & 63, w = tid >> 6;
  const int lr = lane & 15, lh = lane >> 4;
  const float scale2 = 0.08838834764831845f * 1.44269504088896340736f;  // /sqrt(128)*log2(e)
  const f32x4 zf = {0.f, 0.f, 0.f, 0.f};

  for (int half = 0; half < 2; ++half) {
    const int qt = half ? (31 - blockIdx.x) : blockIdx.x;
    const int q0 = qt * 64;

    short8 qf[4];
    {
      const unsigned short* qbase = qkv + (size_t)(q0 + w * 16 + lr) * QKV_LD + head * 128;
#pragma unroll
      for (int kd = 0; kd < 4; ++kd) qf[kd] = *(const short8*)(qbase + kd * 32 + lh * 8);
    }
    f32x4 oacc[8];
#pragma unroll
    for (int vt = 0; vt < 8; ++vt) oacc[vt] = zf;
    float Mr[4], Lr[4];
#pragma unroll
    for (int r = 0; r < 4; ++r) { Mr[r] = -INFINITY; Lr[r] = 0.f; }

    const int nt = qt + 1;
    for (int t = 0; t < nt; ++t) {
      const int kv0 = t * KVB;
      __syncthreads();
      // stage K: 64 rows x 256B, pre-swizzled source chunks
#pragma unroll
      for (int c = 0; c < 4; ++c) {
        const int s = c * 256 + w * 64 + lane;
        const int row = s >> 4, cp = s & 15;
        gl16(qkv + (size_t)(kv0 + row) * QKV_LD + 4096 + hkv * 128 + ((cp ^ (row & 7)) * 8),
             (char*)Ks + (c * 256 + w * 64) * 16);
      }
      // stage V^T: 128 d-rows x 128B, pre-swizzled source chunks
#pragma unroll
      for (int c = 0; c < 4; ++c) {
        const int s = c * 256 + w * 64 + lane;
        const int row = s >> 3, cp = s & 7;
        gl16(vtg + (size_t)(hkv * 128 + row) * TOK + kv0 + ((cp ^ (row & 7)) * 8),
             (char*)Vt + (c * 256 + w * 64) * 16);
      }
      __syncthreads();

      // QK^T: S[16 q][64 kv] per wave
      f32x4 sacc[4];
#pragma unroll
      for (int ct = 0; ct < 4; ++ct) {
        sacc[ct] = zf;
        const int row = ct * 16 + lr;
#pragma unroll
        for (int kd = 0; kd < 4; ++kd) {
          const short8 kf = *(const short8*)((const char*)Ks + row * 256 +
                                             (((kd * 4 + lh) ^ (row & 7)) * 16));
          sacc[ct] = mfma16(qf[kd], kf, sacc[ct]);
        }
      }

      // online softmax (rows on 16-lane groups), exp2 domain
      float scv[4], pv[4][4];
#pragma unroll
      for (int r = 0; r < 4; ++r) {
        const int qrow = q0 + w * 16 + 4 * lh + r;
        float s0 = sacc[0][r] * scale2;
        float s1 = sacc[1][r] * scale2;
        float s2 = sacc[2][r] * scale2;
        float s3 = sacc[3][r] * scale2;
        if (kv0 + lr > qrow) s0 = -INFINITY;
        if (kv0 + 16 + lr > qrow) s1 = -INFINITY;
        if (kv0 + 32 + lr > qrow) s2 = -INFINITY;
        if (kv0 + 48 + lr > qrow) s3 = -INFINITY;
        float tmax = fmaxf(fmaxf(s0, s1), fmaxf(s2, s3));
        tmax = fmaxf(tmax, __shfl_xor(tmax, 1, 16));
        tmax = fmaxf(tmax, __shfl_xor(tmax, 2, 16));
        tmax = fmaxf(tmax, __shfl_xor(tmax, 4, 16));
        tmax = fmaxf(tmax, __shfl_xor(tmax, 8, 16));
        const float mnew = fmaxf(Mr[r], tmax);
        const float sc = fexp2(Mr[r] - mnew);
        Mr[r] = mnew;
        const float p0 = fexp2(s0 - mnew);
        const float p1 = fexp2(s1 - mnew);
        const float p2 = fexp2(s2 - mnew);
        const float p3 = fexp2(s3 - mnew);
        float ps = (p0 + p1) + (p2 + p3);
        ps += __shfl_xor(ps, 1, 16);
        ps += __shfl_xor(ps, 2, 16);
        ps += __shfl_xor(ps, 4, 16);
        ps += __shfl_xor(ps, 8, 16);
        Lr[r] = Lr[r] * sc + ps;
        scv[r] = sc;
        pv[r][0] = p0; pv[r][1] = p1; pv[r][2] = p2; pv[r][3] = p3;
      }
#pragma unroll
      for (int vt = 0; vt < 8; ++vt)
#pragma unroll
        for (int r = 0; r < 4; ++r) oacc[vt][r] *= scv[r];

      // P -> per-wave LDS (stride 72 >= 64 kv), then PV
      unsigned short* pw = Ps[w];
#pragma unroll
      for (int r = 0; r < 4; ++r)
#pragma unroll
        for (int ct = 0; ct < 4; ++ct)
          pw[(4 * lh + r) * PS_LD + ct * 16 + lr] = f2bf(pv[r][ct]);
      asm volatile("s_waitcnt lgkmcnt(0)" ::: "memory");
      short8 pf[2];
      pf[0] = *(const short8*)(pw + lr * PS_LD + lh * 8);
      pf[1] = *(const short8*)(pw + lr * PS_LD + 32 + lh * 8);
#pragma unroll
      for (int vt = 0; vt < 8; ++vt) {
        const int d = vt * 16 + lr;
#pragma unroll
        for (int kb = 0; kb < 2; ++kb) {
          const short8 vf = *(const short8*)((const char*)Vt + d * 128 +
                                             (((kb * 4 + lh) ^ (lr & 7)) * 16));
          oacc[vt] = mfma16(pf[kb], vf, oacc[vt]);
        }
      }
    }

    // epilogue for this q-tile
#pragma unroll
    for (int r = 0; r < 4; ++r) {
      const float inv = 1.0f / Lr[r];
      const size_t rowoff = (size_t)(q0 + w * 16 + 4 * lh + r) * DMODEL + head * 128;
#pragma unroll
      for (int vt = 0; vt < 8; ++vt)
        aout[rowoff + vt * 16 + lr] = f2bf(oacc[vt][r] * inv);
    }
  }
}

extern "C" void kernel_launch(void* const* d_in, const int* in_sizes, int n_in,
                              void* d_out, int out_size, void* d_ws, size_t ws_size,
                              hipStream_t stream) {
  (void)in_sizes; (void)n_in; (void)out_size; (void)ws_size;
  const float* x     = (const float*)d_in[0];
  const float* r_cos = (const float*)d_in[1];
  const float* r_sin = (const float*)d_in[2];
  const float* wnorm = (const float*)d_in[3];
  const float* wq    = (const float*)d_in[4];
  const float* wk    = (const float*)d_in[5];
  const float* wv    = (const float*)d_in[6];
  const float* wo    = (const float*)d_in[7];

  // ws layout (bf16 elems): bufA 8.39M | qkvb 10.49M | wT 25.17M | vtg 2.10M = 92.3MB
  unsigned short* bufA = (unsigned short*)d_ws;                  // h, later attn-out
  unsigned short* qkvb = bufA + (size_t)TOK * DMODEL;            // [2048][5120]
  unsigned short* wT   = qkvb + (size_t)TOK * QKV_LD;            // wqkv^T, later wo^T
  unsigned short* vtg  = wT + (size_t)6144 * DMODEL;             // V^T [1024][2048]

  k_rmsnorm<<<TOK, 256, 0, stream>>>(x, wnorm, bufA);
  k_wconvert<<<dim3(64, 64), 256, 0, stream>>>(wq, wT, DMODEL, 4096);
  k_wconvert<<<dim3(16, 64), 256, 0, stream>>>(wk, wT + (size_t)4096 * DMODEL, DMODEL, 1024);
  k_wconvert<<<dim3(16, 64), 256, 0, stream>>>(wv, wT + (size_t)5120 * DMODEL, DMODEL, 1024);
  k_gemm<0><<<dim3(48, 16), 256, 0, stream>>>(bufA, wT, nullptr, qkvb, vtg, TOK, 6144, DMODEL);
  k_wconvert<<<dim3(64, 64), 256, 0, stream>>>(wo, wT, DMODEL, 4096);   // overlay: wo^T
  k_rope<<<dim3(10, TOK), 256, 0, stream>>>(qkvb, r_cos, r_sin);
  k_attn<<<dim3(16, 32), 256, 0, stream>>>(qkvb, vtg, bufA);
  k_gemm<1><<<dim3(32, 16), 256, 0, stream>>>(bufA, wT, x, d_out, vtg, TOK, DMODEL, DMODEL);
}

// Round 4
// 334.952 us; speedup vs baseline: 1.6047x; 1.2008x over previous
//
#include <hip/hip_runtime.h>
#include <stdint.h>
#include <math.h>

#define TOK 2048
#define DMODEL 4096
#define QKV_LD 5120   // q(4096) | k(1024); V goes transposed to vtg
#define KVB 64
#define PS_LD 72      // 64 kv + 8 pad (P-tile LDS stride)

typedef __attribute__((ext_vector_type(8))) short short8;
typedef __attribute__((ext_vector_type(4))) short short4v;
typedef __attribute__((ext_vector_type(8))) __bf16 bf16x8;
typedef __attribute__((ext_vector_type(4))) float f32x4;

__device__ __forceinline__ unsigned short f2bf(float f) {
  unsigned u = __float_as_uint(f);
  u += 0x7fffu + ((u >> 16) & 1u);   // RNE
  return (unsigned short)(u >> 16);
}

__device__ __forceinline__ void gl16(const void* g, void* l) {
  __builtin_amdgcn_global_load_lds((__attribute__((address_space(1))) void*)g,
                                   (__attribute__((address_space(3))) void*)l,
                                   16, 0, 0);
}

__device__ __forceinline__ f32x4 mfma16(short8 a, short8 b, f32x4 c) {
  return __builtin_amdgcn_mfma_f32_16x16x32_bf16(__builtin_bit_cast(bf16x8, a),
                                                 __builtin_bit_cast(bf16x8, b),
                                                 c, 0, 0, 0);
}

__device__ __forceinline__ float fexp2(float x) {
  float r;
  asm("v_exp_f32 %0, %1" : "=v"(r) : "v"(x));
  return r;
}

// ---------------- RMSNorm: fp32 x -> bf16 h ----------------
__global__ __launch_bounds__(256) void k_rmsnorm(const float* __restrict__ x,
                                                 const float* __restrict__ w,
                                                 unsigned short* __restrict__ h) {
  const int row = blockIdx.x;
  const float* xr = x + (size_t)row * DMODEL;
  float4 v[4];
  float ss = 0.f;
#pragma unroll
  for (int i = 0; i < 4; ++i) {
    v[i] = *(const float4*)(xr + threadIdx.x * 4 + i * 1024);
    ss += v[i].x * v[i].x + v[i].y * v[i].y + v[i].z * v[i].z + v[i].w * v[i].w;
  }
#pragma unroll
  for (int m = 1; m < 64; m <<= 1) ss += __shfl_xor(ss, m, 64);
  __shared__ float ws4[4];
  if ((threadIdx.x & 63) == 0) ws4[threadIdx.x >> 6] = ss;
  __syncthreads();
  const float scale = rsqrtf((ws4[0] + ws4[1] + ws4[2] + ws4[3]) * (1.0f / DMODEL) + 1e-5f);
  unsigned short* hr = h + (size_t)row * DMODEL;
#pragma unroll
  for (int i = 0; i < 4; ++i) {
    int col = threadIdx.x * 4 + i * 1024;
    float4 wv = *(const float4*)(w + col);
    uint2 o;
    o.x = (unsigned)f2bf(v[i].x * scale * wv.x) | ((unsigned)f2bf(v[i].y * scale * wv.y) << 16);
    o.y = (unsigned)f2bf(v[i].z * scale * wv.z) | ((unsigned)f2bf(v[i].w * scale * wv.w) << 16);
    *(uint2*)(hr + col) = o;
  }
}

// ------- Weight convert+transpose: W[K][N] fp32 -> WT[N][K] bf16 -------
__global__ __launch_bounds__(256) void k_wconvert(const float* __restrict__ W,
                                                  unsigned short* __restrict__ WT,
                                                  int K, int N) {
  __shared__ unsigned short tile[64][65];
  const int n0 = blockIdx.x * 64, k0 = blockIdx.y * 64;
  const int t = threadIdx.x;
  {
    const int r = t >> 2, c0 = (t & 3) * 16;
    const float* src = W + (size_t)(k0 + r) * N + n0 + c0;
#pragma unroll
    for (int i = 0; i < 4; ++i) {
      float4 f = *(const float4*)(src + i * 4);
      tile[r][c0 + i * 4 + 0] = f2bf(f.x);
      tile[r][c0 + i * 4 + 1] = f2bf(f.y);
      tile[r][c0 + i * 4 + 2] = f2bf(f.z);
      tile[r][c0 + i * 4 + 3] = f2bf(f.w);
    }
  }
  __syncthreads();
  {
    const int n = t >> 2, c0 = (t & 3) * 16;
    unsigned short* dst = WT + (size_t)(n0 + n) * K + k0 + c0;
    unsigned short v[16];
#pragma unroll
    for (int i = 0; i < 16; ++i) v[i] = tile[c0 + i][n];
    uint4 o0, o1;
    o0.x = v[0] | ((unsigned)v[1] << 16);  o0.y = v[2] | ((unsigned)v[3] << 16);
    o0.z = v[4] | ((unsigned)v[5] << 16);  o0.w = v[6] | ((unsigned)v[7] << 16);
    o1.x = v[8] | ((unsigned)v[9] << 16);  o1.y = v[10] | ((unsigned)v[11] << 16);
    o1.z = v[12] | ((unsigned)v[13] << 16); o1.w = v[14] | ((unsigned)v[15] << 16);
    *(uint4*)dst = o0;
    *(uint4*)(dst + 8) = o1;
  }
}

// ======== Big-tile pipelined GEMM: A[M][K] x BT[N][K] -> C[M][N] ========
// 8 waves (2M x 4N), BK=64, double-buffered dynamic LDS, XOR-swizzled tiles,
// all next-tile global_load_lds issued up front, one barrier per K-tile.
__device__ __forceinline__ short8 rdfrag(const unsigned short* buf, int row, int kc) {
  return *(const short8*)((const char*)buf + row * 128 + ((kc ^ (row & 7)) << 4));
}

template <int BM, int BN>
__device__ __forceinline__ void stage_tile(const unsigned short* __restrict__ A,
                                           const unsigned short* __restrict__ BT,
                                           unsigned short* __restrict__ buf,
                                           int m0, int n0, int K, int kt, int tid) {
  constexpr int ALOADS = BM * 8 / 512;
  constexpr int BLOADS = BN * 8 / 512;
  unsigned short* bbuf = buf + BM * 64;
#pragma unroll
  for (int i = 0; i < ALOADS; ++i) {
    const int s = i * 512 + tid, row = s >> 3, ch = s & 7;
    gl16(A + (size_t)(m0 + row) * K + kt + ((ch ^ (row & 7)) << 3), (char*)buf + s * 16);
  }
#pragma unroll
  for (int i = 0; i < BLOADS; ++i) {
    const int s = i * 512 + tid, row = s >> 3, ch = s & 7;
    gl16(BT + (size_t)(n0 + row) * K + kt + ((ch ^ (row & 7)) << 3), (char*)bbuf + s * 16);
  }
}

// MODE=0: qkv epilogue (cols<5120 -> bf16 qkvb stride QKV_LD; cols>=5120 -> vtg
//         transposed [col-5120][token]).  MODE=1: fp32 C = acc + resid.
template <int BM, int BN, int MODE, int GXLOG>
__global__ __launch_bounds__(512, 2) void k_gemm_big(const unsigned short* __restrict__ A,
                                                     const unsigned short* __restrict__ BT,
                                                     const float* __restrict__ resid,
                                                     void* __restrict__ Cout,
                                                     unsigned short* __restrict__ vtg,
                                                     int M, int N, int K) {
  extern __shared__ __align__(16) unsigned short lds[];
  constexpr int MREP = BM / 32;          // per-wave m fragments
  constexpr int NREP = BN / 64;          // per-wave n fragments
  constexpr int MH = MREP / 2;
  constexpr int NH0 = (NREP + 1) / 2;
  constexpr int NH1 = NREP - NH0;
  constexpr int TILE = (BM + BN) * 64;   // elements per buffer

  const int tid = threadIdx.x, lane = tid & 63;
  const int w = tid >> 6, wm = w >> 2, wn = w & 3;
  const int lr = lane & 15, lh = lane >> 4;

  // XCD-chunked bijective block swizzle (nwg % 8 == 0)
  const int nwg = gridDim.x * gridDim.y;
  const int wg0 = blockIdx.y * gridDim.x + blockIdx.x;
  const int swz = (wg0 & 7) * (nwg >> 3) + (wg0 >> 3);
  const int m0 = (swz >> GXLOG) * BM;
  const int n0 = (swz & ((1 << GXLOG) - 1)) * BN;

  const f32x4 zf = {0.f, 0.f, 0.f, 0.f};
  f32x4 acc[MREP][NREP];
#pragma unroll
  for (int i = 0; i < MREP; ++i) {
#pragma unroll
    for (int j = 0; j < NREP; ++j) acc[i][j] = zf;
  }

  const int arow0 = wm * (BM / 2);
  const int brow0 = wn * (BN / 4);
  const int NT = K >> 6;
  int cur = 0;

  stage_tile<BM, BN>(A, BT, lds, m0, n0, K, 0, tid);
  __syncthreads();

  for (int t = 0; t < NT; ++t) {
    const unsigned short* abuf = lds + cur * TILE;
    const unsigned short* bbuf = abuf + BM * 64;
    if (t + 1 < NT)
      stage_tile<BM, BN>(A, BT, lds + (cur ^ 1) * TILE, m0, n0, K, (t + 1) << 6, tid);

    short8 afr[MH][2], bfr[NH0][2];
    // ---- phase 0: A half 0 + B group 0
#pragma unroll
    for (int mr = 0; mr < MH; ++mr) {
#pragma unroll
      for (int kk = 0; kk < 2; ++kk)
        afr[mr][kk] = rdfrag(abuf, arow0 + mr * 16 + lr, kk * 4 + lh);
    }
#pragma unroll
    for (int nr = 0; nr < NH0; ++nr) {
#pragma unroll
      for (int kk = 0; kk < 2; ++kk)
        bfr[nr][kk] = rdfrag(bbuf, brow0 + nr * 16 + lr, kk * 4 + lh);
    }
    __builtin_amdgcn_s_setprio(1);
#pragma unroll
    for (int mr = 0; mr < MH; ++mr) {
#pragma unroll
      for (int nr = 0; nr < NH0; ++nr) {
#pragma unroll
        for (int kk = 0; kk < 2; ++kk)
          acc[mr][nr] = mfma16(afr[mr][kk], bfr[nr][kk], acc[mr][nr]);
      }
    }
    __builtin_amdgcn_s_setprio(0);
    // ---- phase 1: B group 1
#pragma unroll
    for (int nr = 0; nr < NH1; ++nr) {
#pragma unroll
      for (int kk = 0; kk < 2; ++kk)
        bfr[nr][kk] = rdfrag(bbuf, brow0 + (NH0 + nr) * 16 + lr, kk * 4 + lh);
    }
    __builtin_amdgcn_s_setprio(1);
#pragma unroll
    for (int mr = 0; mr < MH; ++mr) {
#pragma unroll
      for (int nr = 0; nr < NH1; ++nr) {
#pragma unroll
        for (int kk = 0; kk < 2; ++kk)
          acc[mr][NH0 + nr] = mfma16(afr[mr][kk], bfr[nr][kk], acc[mr][NH0 + nr]);
      }
    }
    __builtin_amdgcn_s_setprio(0);
    // ---- phase 2: A half 1 (B group 1 still in regs)
#pragma unroll
    for (int mr = 0; mr < MH; ++mr) {
#pragma unroll
      for (int kk = 0; kk < 2; ++kk)
        afr[mr][kk] = rdfrag(abuf, arow0 + (MH + mr) * 16 + lr, kk * 4 + lh);
    }
    __builtin_amdgcn_s_setprio(1);
#pragma unroll
    for (int mr = 0; mr < MH; ++mr) {
#pragma unroll
      for (int nr = 0; nr < NH1; ++nr) {
#pragma unroll
        for (int kk = 0; kk < 2; ++kk)
          acc[MH + mr][NH0 + nr] = mfma16(afr[mr][kk], bfr[nr][kk], acc[MH + mr][NH0 + nr]);
      }
    }
    __builtin_amdgcn_s_setprio(0);
    // ---- phase 3: B group 0 reload
#pragma unroll
    for (int nr = 0; nr < NH0; ++nr) {
#pragma unroll
      for (int kk = 0; kk < 2; ++kk)
        bfr[nr][kk] = rdfrag(bbuf, brow0 + nr * 16 + lr, kk * 4 + lh);
    }
    __builtin_amdgcn_s_setprio(1);
#pragma unroll
    for (int mr = 0; mr < MH; ++mr) {
#pragma unroll
      for (int nr = 0; nr < NH0; ++nr) {
#pragma unroll
        for (int kk = 0; kk < 2; ++kk)
          acc[MH + mr][nr] = mfma16(afr[mr][kk], bfr[nr][kk], acc[MH + mr][nr]);
      }
    }
    __builtin_amdgcn_s_setprio(0);

    __syncthreads();   // drains next-tile stage (vmcnt) + read-done for overwrite
    cur ^= 1;
  }

  // ---- epilogue: C row = 4*lh + r, col = lr within each 16x16 tile
#pragma unroll
  for (int ai = 0; ai < MREP; ++ai) {
#pragma unroll
    for (int ni = 0; ni < NREP; ++ni) {
      const int colg = n0 + wn * (BN / 4) + ni * 16 + lr;
      const int rowg0 = m0 + wm * (BM / 2) + ai * 16 + 4 * lh;
      if (MODE == 1) {
#pragma unroll
        for (int r = 0; r < 4; ++r)
          ((float*)Cout)[(size_t)(rowg0 + r) * N + colg] =
              acc[ai][ni][r] + resid[(size_t)(rowg0 + r) * N + colg];
      } else if (colg >= 5120) {
        short4v o;
#pragma unroll
        for (int r = 0; r < 4; ++r) o[r] = (short)f2bf(acc[ai][ni][r]);
        *(short4v*)(vtg + (size_t)(colg - 5120) * TOK + rowg0) = o;
      } else {
#pragma unroll
        for (int r = 0; r < 4; ++r)
          ((unsigned short*)Cout)[(size_t)(rowg0 + r) * QKV_LD + colg] = f2bf(acc[ai][ni][r]);
      }
    }
  }
}

// ---------------- RoPE (in-place on q|k columns 0..5119) ----------------
__global__ __launch_bounds__(256) void k_rope(unsigned short* __restrict__ qkv,
                                              const float* __restrict__ rc,
                                              const float* __restrict__ rs) {
  const int row = blockIdx.y;
  const int p = blockIdx.x * 256 + threadIdx.x;  // pair 0..2559
  const int col = p * 2;
  const int d = col & 127;
  unsigned short* ptr = qkv + (size_t)row * QKV_LD + col;
  const unsigned both = *(const unsigned*)ptr;
  const float x0 = __uint_as_float((both & 0xffffu) << 16);
  const float x1 = __uint_as_float(both & 0xffff0000u);
  const float c0 = rc[row * 128 + d], c1 = rc[row * 128 + d + 1];
  const float s0 = rs[row * 128 + d], s1 = rs[row * 128 + d + 1];
  const float y0 = x0 * c0 - x1 * s0;
  const float y1 = x1 * c1 + x0 * s1;
  *(unsigned*)ptr = (unsigned)f2bf(y0) | ((unsigned)f2bf(y1) << 16);
}

// ---------------- Flash attention, causal, GQA ----------------
// grid (16 pairs, 32 heads); block = 4 waves x 16 q-rows = 64 q-rows.
// Each block does q-tile i then q-tile 31-i -> exactly 33 KV-tiles of 64.
__global__ __launch_bounds__(256) void k_attn(const unsigned short* __restrict__ qkv,
                                              const unsigned short* __restrict__ vtg,
                                              unsigned short* __restrict__ aout) {
  __shared__ __align__(16) unsigned short Ks[KVB * 128];      // 16KB, XOR-swizzled
  __shared__ __align__(16) unsigned short Vt[128 * KVB];      // 16KB, XOR-swizzled (V^T)
  __shared__ __align__(16) unsigned short Ps[4][16 * PS_LD];  // per-wave P, stride 72
  const int head = blockIdx.y;
  const int hkv = head >> 2;
  const int tid = threadIdx.x, lane = tid & 63, w = tid >> 6;
  const int lr = lane & 15, lh = lane >> 4;
  const float scale2 = 0.08838834764831845f * 1.44269504088896340736f;  // /sqrt(128)*log2(e)
  const f32x4 zf = {0.f, 0.f, 0.f, 0.f};

  for (int half = 0; half < 2; ++half) {
    const int qt = half ? (31 - blockIdx.x) : blockIdx.x;
    const int q0 = qt * 64;

    short8 qf[4];
    {
      const unsigned short* qbase = qkv + (size_t)(q0 + w * 16 + lr) * QKV_LD + head * 128;
#pragma unroll
      for (int kd = 0; kd < 4; ++kd) qf[kd] = *(const short8*)(qbase + kd * 32 + lh * 8);
    }
    f32x4 oacc[8];
#pragma unroll
    for (int vt = 0; vt < 8; ++vt) oacc[vt] = zf;
    float Mr[4], Lr[4];
#pragma unroll
    for (int r = 0; r < 4; ++r) { Mr[r] = -INFINITY; Lr[r] = 0.f; }

    const int nt = qt + 1;
    for (int t = 0; t < nt; ++t) {
      const int kv0 = t * KVB;
      __syncthreads();
      // stage K: 64 rows x 256B, pre-swizzled source chunks
#pragma unroll
      for (int c = 0; c < 4; ++c) {
        const int s = c * 256 + w * 64 + lane;
        const int row = s >> 4, cp = s & 15;
        gl16(qkv + (size_t)(kv0 + row) * QKV_LD + 4096 + hkv * 128 + ((cp ^ (row & 7)) * 8),
             (char*)Ks + (c * 256 + w * 64) * 16);
      }
      // stage V^T: 128 d-rows x 128B, pre-swizzled source chunks
#pragma unroll
      for (int c = 0; c < 4; ++c) {
        const int s = c * 256 + w * 64 + lane;
        const int row = s >> 3, cp = s & 7;
        gl16(vtg + (size_t)(hkv * 128 + row) * TOK + kv0 + ((cp ^ (row & 7)) * 8),
             (char*)Vt + (c * 256 + w * 64) * 16);
      }
      __syncthreads();

      // QK^T: S[16 q][64 kv] per wave
      f32x4 sacc[4];
#pragma unroll
      for (int ct = 0; ct < 4; ++ct) {
        sacc[ct] = zf;
        const int row = ct * 16 + lr;
#pragma unroll
        for (int kd = 0; kd < 4; ++kd) {
          const short8 kf = *(const short8*)((const char*)Ks + row * 256 +
                                             (((kd * 4 + lh) ^ (row & 7)) * 16));
          sacc[ct] = mfma16(qf[kd], kf, sacc[ct]);
        }
      }

      // online softmax (rows on 16-lane groups), exp2 domain
      float scv[4], pv[4][4];
#pragma unroll
      for (int r = 0; r < 4; ++r) {
        const int qrow = q0 + w * 16 + 4 * lh + r;
        float s0 = sacc[0][r] * scale2;
        float s1 = sacc[1][r] * scale2;
        float s2 = sacc[2][r] * scale2;
        float s3 = sacc[3][r] * scale2;
        if (kv0 + lr > qrow) s0 = -INFINITY;
        if (kv0 + 16 + lr > qrow) s1 = -INFINITY;
        if (kv0 + 32 + lr > qrow) s2 = -INFINITY;
        if (kv0 + 48 + lr > qrow) s3 = -INFINITY;
        float tmax = fmaxf(fmaxf(s0, s1), fmaxf(s2, s3));
        tmax = fmaxf(tmax, __shfl_xor(tmax, 1, 16));
        tmax = fmaxf(tmax, __shfl_xor(tmax, 2, 16));
        tmax = fmaxf(tmax, __shfl_xor(tmax, 4, 16));
        tmax = fmaxf(tmax, __shfl_xor(tmax, 8, 16));
        const float mnew = fmaxf(Mr[r], tmax);
        const float sc = fexp2(Mr[r] - mnew);
        Mr[r] = mnew;
        const float p0 = fexp2(s0 - mnew);
        const float p1 = fexp2(s1 - mnew);
        const float p2 = fexp2(s2 - mnew);
        const float p3 = fexp2(s3 - mnew);
        float ps = (p0 + p1) + (p2 + p3);
        ps += __shfl_xor(ps, 1, 16);
        ps += __shfl_xor(ps, 2, 16);
        ps += __shfl_xor(ps, 4, 16);
        ps += __shfl_xor(ps, 8, 16);
        Lr[r] = Lr[r] * sc + ps;
        scv[r] = sc;
        pv[r][0] = p0; pv[r][1] = p1; pv[r][2] = p2; pv[r][3] = p3;
      }
#pragma unroll
      for (int vt = 0; vt < 8; ++vt) {
#pragma unroll
        for (int r = 0; r < 4; ++r) oacc[vt][r] *= scv[r];
      }

      // P -> per-wave LDS (stride 72 >= 64 kv), then PV
      unsigned short* pw = Ps[w];
#pragma unroll
      for (int r = 0; r < 4; ++r) {
#pragma unroll
        for (int ct = 0; ct < 4; ++ct)
          pw[(4 * lh + r) * PS_LD + ct * 16 + lr] = f2bf(pv[r][ct]);
      }
      asm volatile("s_waitcnt lgkmcnt(0)" ::: "memory");
      short8 pf[2];
      pf[0] = *(const short8*)(pw + lr * PS_LD + lh * 8);
      pf[1] = *(const short8*)(pw + lr * PS_LD + 32 + lh * 8);
      __builtin_amdgcn_s_setprio(1);
#pragma unroll
      for (int vt = 0; vt < 8; ++vt) {
        const int d = vt * 16 + lr;
#pragma unroll
        for (int kb = 0; kb < 2; ++kb) {
          const short8 vf = *(const short8*)((const char*)Vt + d * 128 +
                                             (((kb * 4 + lh) ^ (lr & 7)) * 16));
          oacc[vt] = mfma16(pf[kb], vf, oacc[vt]);
        }
      }
      __builtin_amdgcn_s_setprio(0);
    }

    // epilogue for this q-tile
#pragma unroll
    for (int r = 0; r < 4; ++r) {
      const float inv = 1.0f / Lr[r];
      const size_t rowoff = (size_t)(q0 + w * 16 + 4 * lh + r) * DMODEL + head * 128;
#pragma unroll
      for (int vt = 0; vt < 8; ++vt)
        aout[rowoff + vt * 16 + lr] = f2bf(oacc[vt][r] * inv);
    }
  }
}

extern "C" void kernel_launch(void* const* d_in, const int* in_sizes, int n_in,
                              void* d_out, int out_size, void* d_ws, size_t ws_size,
                              hipStream_t stream) {
  (void)in_sizes; (void)n_in; (void)out_size; (void)ws_size;
  const float* x     = (const float*)d_in[0];
  const float* r_cos = (const float*)d_in[1];
  const float* r_sin = (const float*)d_in[2];
  const float* wnorm = (const float*)d_in[3];
  const float* wq    = (const float*)d_in[4];
  const float* wk    = (const float*)d_in[5];
  const float* wv    = (const float*)d_in[6];
  const float* wo    = (const float*)d_in[7];

  // ws layout (bf16 elems): bufA 8.39M | qkvb 10.49M | wT 25.17M | vtg 2.10M = 92.3MB
  unsigned short* bufA = (unsigned short*)d_ws;                  // h, later attn-out
  unsigned short* qkvb = bufA + (size_t)TOK * DMODEL;            // [2048][5120]
  unsigned short* wT   = qkvb + (size_t)TOK * QKV_LD;            // wqkv^T, later wo^T
  unsigned short* vtg  = wT + (size_t)6144 * DMODEL;             // V^T [1024][2048]

  // dynamic-LDS caps (idempotent, host-side; safe under graph capture)
  hipFuncSetAttribute((const void*)k_gemm_big<256, 192, 0, 5>,
                      hipFuncAttributeMaxDynamicSharedMemorySize, 4 * (256 + 192) * 64);
  hipFuncSetAttribute((const void*)k_gemm_big<128, 256, 1, 4>,
                      hipFuncAttributeMaxDynamicSharedMemorySize, 4 * (128 + 256) * 64);

  k_rmsnorm<<<TOK, 256, 0, stream>>>(x, wnorm, bufA);
  k_wconvert<<<dim3(64, 64), 256, 0, stream>>>(wq, wT, DMODEL, 4096);
  k_wconvert<<<dim3(16, 64), 256, 0, stream>>>(wk, wT + (size_t)4096 * DMODEL, DMODEL, 1024);
  k_wconvert<<<dim3(16, 64), 256, 0, stream>>>(wv, wT + (size_t)5120 * DMODEL, DMODEL, 1024);
  k_gemm_big<256, 192, 0, 5><<<dim3(32, 8), 512, 4 * (256 + 192) * 64, stream>>>(
      bufA, wT, nullptr, qkvb, vtg, TOK, 6144, DMODEL);
  k_wconvert<<<dim3(64, 64), 256, 0, stream>>>(wo, wT, DMODEL, 4096);   // overlay: wo^T
  k_rope<<<dim3(10, TOK), 256, 0, stream>>>(qkvb, r_cos, r_sin);
  k_attn<<<dim3(16, 32), 256, 0, stream>>>(qkvb, vtg, bufA);
  k_gemm_big<128, 256, 1, 4><<<dim3(16, 16), 512, 4 * (128 + 256) * 64, stream>>>(
      bufA, wT, x, d_out, nullptr, TOK, DMODEL, DMODEL);
}